// Round 19
// baseline (398.326 us; speedup 1.0000x reference)
//
#include <hip/hip_runtime.h>
#include <stdint.h>

#define N_NODES 50000
#define N_PAD   50048      // 391 * 128
#define GQ      8
#define EE      400000
#define DIM     512
#define CAPE    128        // per-node edge-slot capacity (Poisson(8)+1 max ~35)
#define NBLK_SCAN 196
#define EDGE_BLOCKS 1024   // measured curve minimum: 37% occ, 130MB fetch, 65.5us

typedef __attribute__((ext_vector_type(8))) __bf16 bf16x8;
typedef __attribute__((ext_vector_type(4))) float f32x4;
typedef __attribute__((ext_vector_type(2))) float f32x2;

// ---------------- helpers ----------------
__device__ __forceinline__ unsigned short f2bf(float f){
  unsigned u = __float_as_uint(f);
  return (unsigned short)((u + 0x7fffu + ((u >> 16) & 1u)) >> 16);
}
__device__ __forceinline__ unsigned pk2(float lo, float hi){
  return (unsigned)f2bf(lo) | ((unsigned)f2bf(hi) << 16);
}
__device__ __forceinline__ float dot4(float4 a, float4 b){ return a.x*b.x + a.y*b.y + a.z*b.z + a.w*b.w; }
__device__ __forceinline__ float wredSum(float v){
#pragma unroll
  for (int o = 32; o > 0; o >>= 1) v += __shfl_xor(v, o, 64);
  return v;
}
__device__ __forceinline__ float rlanef(float v, int l){
  return __int_as_float(__builtin_amdgcn_readlane(__float_as_int(v), l));
}
__device__ __forceinline__ void gload_lds16(const void* g, void* l){
  __builtin_amdgcn_global_load_lds((__attribute__((address_space(1))) void*)g,
                                   (__attribute__((address_space(3))) void*)l, 16, 0, 0);
}
// fp8 e4m3 HW codec (self-consistent encode+decode on gfx950)
__device__ __forceinline__ unsigned char f2fp8(float x){
  return (unsigned char)__builtin_amdgcn_cvt_pk_fp8_f32(x, x, 0, false);
}
__device__ __forceinline__ unsigned pk4f8(float a, float b, float c, float d){
  unsigned w = (unsigned)__builtin_amdgcn_cvt_pk_fp8_f32(a, b, 0, false);
  return (unsigned)__builtin_amdgcn_cvt_pk_fp8_f32(c, d, (int)w, true);
}
// half-row consume: 4B = 4 fp8 channels -> 2 packed FMAs; al is SGPR-uniform
__device__ __forceinline__ void consume4(f32x2* ac, unsigned u, float al){
  f32x2 p0 = __builtin_amdgcn_cvt_pk_f32_fp8(u, false);
  f32x2 p1 = __builtin_amdgcn_cvt_pk_f32_fp8(u, true);
  ac[0] += al * p0;
  ac[1] += al * p1;
}

// ---------------- workspace layout ----------------
static constexpr size_t AL(size_t x){ return (x + 255) & ~(size_t)255; }
static constexpr size_t OFF_XBF   = 0;
static constexpr size_t OFF_HF8   = OFF_XBF   + AL((size_t)N_PAD * DIM * 2);
static constexpr size_t OFF_HCV8  = OFF_HF8   + AL((size_t)N_PAD * DIM);
static constexpr size_t OFF_CAP   = OFF_HCV8  + AL((size_t)N_NODES * DIM);
static constexpr size_t OFF_WTBF  = OFF_CAP   + AL((size_t)N_NODES * CAPE * 8);
static constexpr size_t OFF_WNT   = OFF_WTBF  + AL((size_t)DIM * DIM * 2);
static constexpr size_t OFF_W1T   = OFF_WNT   + AL((size_t)DIM * DIM * 4);
static constexpr size_t OFF_WSS   = OFF_W1T   + AL((size_t)DIM * DIM * 4);
static constexpr size_t OFF_WSD   = OFF_WSS   + AL((size_t)DIM * 4);
static constexpr size_t OFF_AS    = OFF_WSD   + AL((size_t)DIM * 4);
static constexpr size_t OFF_AD    = OFF_AS    + AL((size_t)N_NODES * 4);
static constexpr size_t OFF_GATE  = OFF_AD    + AL((size_t)N_NODES * 4);
static constexpr size_t OFF_CNT   = OFF_GATE  + AL((size_t)N_NODES * 4);
static constexpr size_t OFF_GSUM  = OFF_CNT   + AL((size_t)N_NODES * 4);
static constexpr size_t OFF_PP    = OFF_GSUM  + AL((size_t)GQ * 4);
static constexpr size_t OFF_POOL  = OFF_PP    + AL((size_t)GQ * DIM * 4);
static constexpr size_t OFF_Z1    = OFF_POOL  + AL((size_t)GQ * DIM * 4);

// ---------------- kernels ----------------

// fused: init (cnt/gsum/pp) + ws_s/ws_d = W@att_{src,dst} + 3x 512x512 transpose
__global__ void k_setup(const float* __restrict__ W, const float* __restrict__ atS,
                        const float* __restrict__ atD, const float* __restrict__ Wn,
                        const float* __restrict__ W1,
                        float* ws_s, float* ws_d,
                        unsigned short* __restrict__ WtBf, float* __restrict__ WnT,
                        float* __restrict__ W1T,
                        int* cnt, float* gsum, float* pp){
  __shared__ float tile[64][65];
  int bx = blockIdx.x;
  if (bx < NBLK_SCAN){
    int i = bx * 256 + threadIdx.x;
    if (i < N_NODES) cnt[i] = 1;                    // slot 0 = self-loop
    if (i < GQ) gsum[i] = 0.f;
    if (i < GQ * DIM) pp[i] = 0.f;
    if (bx < 128){
      int wid = threadIdx.x >> 6, lane = threadIdx.x & 63;
      int k = bx * 4 + wid;                         // 0..511
      const float4* row = (const float4*)(W + (size_t)k * DIM);
      float4 r0 = row[lane * 2], r1 = row[lane * 2 + 1];
      const float4* s4 = (const float4*)atS;
      const float4* d4 = (const float4*)atD;
      float vs = dot4(r0, s4[lane * 2]) + dot4(r1, s4[lane * 2 + 1]);
      float vd = dot4(r0, d4[lane * 2]) + dot4(r1, d4[lane * 2 + 1]);
      vs = wredSum(vs); vd = wredSum(vd);
      if (lane == 0){ ws_s[k] = vs; ws_d[k] = vd; }
    }
  } else {
    int tb = bx - NBLK_SCAN;
    int y = tb >> 6, bq = tb & 63;
    const float* src = (y == 0) ? W : (y == 1) ? Wn : W1;
    int bi = bq & 7, bj = bq >> 3;
    int r0 = bi * 64, c0 = bj * 64;
#pragma unroll
    for (int ii = 0; ii < 16; ++ii){
      int idx = ii * 256 + threadIdx.x;
      int r = idx >> 6, c = idx & 63;
      tile[r][c] = src[(size_t)(r0 + r) * DIM + c0 + c];
    }
    __syncthreads();
#pragma unroll
    for (int ii = 0; ii < 16; ++ii){
      int idx = ii * 256 + threadIdx.x;
      int cc = idx >> 6, rr = idx & 63;
      float v = tile[rr][cc];
      size_t o = (size_t)(c0 + cc) * DIM + r0 + rr;
      if (y == 0) WtBf[o] = f2bf(v);
      else if (y == 1) WnT[o] = v;
      else W1T[o] = v;
    }
  }
}

// cast x -> bf16 (zero pad rows), a_s/a_d per row, write self-loop cap slot 0
// (R14-measured config: short blocks)
__global__ __launch_bounds__(256) void k_cast(const float* __restrict__ x,
                                              const float* __restrict__ ws_s,
                                              const float* __restrict__ ws_d,
                                              unsigned short* __restrict__ x_bf,
                                              float* __restrict__ a_s, float* __restrict__ a_d,
                                              int2* __restrict__ cap){
  int wid = threadIdx.x >> 6, lane = threadIdx.x & 63;
  size_t i = (size_t)blockIdx.x * 4 + wid;
  if (i >= N_PAD) return;
  unsigned short* orow = x_bf + i * DIM;
  if (i >= N_NODES){
    ((uint4*)orow)[lane] = make_uint4(0, 0, 0, 0);
    return;
  }
  const float4* xr = (const float4*)(x + i * DIM);
  float4 v0 = xr[lane * 2], v1 = xr[lane * 2 + 1];
  ((uint4*)orow)[lane] = make_uint4(pk2(v0.x, v0.y), pk2(v0.z, v0.w), pk2(v1.x, v1.y), pk2(v1.z, v1.w));
  const float4* s4 = (const float4*)ws_s;
  const float4* d4 = (const float4*)ws_d;
  float vs = dot4(v0, s4[lane * 2]) + dot4(v1, s4[lane * 2 + 1]);
  float vd = dot4(v0, d4[lane * 2]) + dot4(v1, d4[lane * 2 + 1]);
  vs = wredSum(vs); vd = wredSum(vd);
  if (lane == 0){
    a_s[i] = vs; a_d[i] = vd;
    cap[i * CAPE] = make_int2((int)(i << 9), __float_as_int(vs));   // self-loop: byte offset
  }
}

// append edges into fixed-capacity per-dst rows; store PRE-SHIFTED byte offset
__global__ void k_fill(const int* __restrict__ ei, const float* __restrict__ a_s,
                       int* cnt, int2* __restrict__ cap){
  int e = blockIdx.x * 256 + threadIdx.x;
  if (e < EE){
    int s = ei[e], d = ei[EE + e];
    int p = atomicAdd(&cnt[d], 1);
    if (p < CAPE) cap[(size_t)d * CAPE + p] = make_int2(s << 9, __float_as_int(a_s[s]));
  }
}

// h = x_bf @ W (Bt = W^T, bf16). 128x256 strip tile, 16x16x32 MFMA, XOR bank swizzle.
// (R14-measured config: single-buffer; R16 dbuf was neutral -> reverted)
// Epilogue stores h as fp8 e4m3 (halves k_edge's gather bytes).
__global__ __launch_bounds__(256, 2) void k_gemm(const unsigned short* __restrict__ A,
                                                 const unsigned short* __restrict__ Bt,
                                                 unsigned char* __restrict__ H8){
  __shared__ unsigned short As[128 * 32];   // 8 KB
  __shared__ unsigned short Bs[256 * 32];   // 16 KB
  const int tid = threadIdx.x;
  const int wid = tid >> 6, lane = tid & 63, quad = lane >> 4, l16 = lane & 15;
  const int m0 = blockIdx.x * 128, n0 = blockIdx.y * 256;
  const int wm = (wid & 1) * 64, wn = (wid >> 1) * 128;
  const int qa = quad ^ ((l16 >> 1) & 3);           // swizzled chunk for reads
  f32x4 acc[4][8] = {};
  for (int kt = 0; kt < 16; ++kt){
    const int k0 = kt * 32;
    __syncthreads();
#pragma unroll
    for (int r = 0; r < 2; ++r){                    // A: 512 16B-chunks
      int p = r * 256 + tid;
      int mm = p >> 2;
      int qg = (p & 3) ^ ((mm >> 1) & 3);
      gload_lds16(A + (size_t)(m0 + mm) * DIM + k0 + qg * 8,
                  As + (size_t)(r * 256 + wid * 64) * 8);
    }
#pragma unroll
    for (int r = 0; r < 4; ++r){                    // B: 1024 16B-chunks
      int p = r * 256 + tid;
      int mm = p >> 2;
      int qg = (p & 3) ^ ((mm >> 1) & 3);
      gload_lds16(Bt + (size_t)(n0 + mm) * DIM + k0 + qg * 8,
                  Bs + (size_t)(r * 256 + wid * 64) * 8);
    }
    __syncthreads();
    bf16x8 af[4], bfr[8];
#pragma unroll
    for (int f = 0; f < 4; ++f)
      af[f]  = *(const bf16x8*)(As + (wm + f * 16 + l16) * 32 + qa * 8);
#pragma unroll
    for (int f = 0; f < 8; ++f)
      bfr[f] = *(const bf16x8*)(Bs + (wn + f * 16 + l16) * 32 + qa * 8);
#pragma unroll
    for (int fm = 0; fm < 4; ++fm)
#pragma unroll
      for (int fn = 0; fn < 8; ++fn)
        acc[fm][fn] = __builtin_amdgcn_mfma_f32_16x16x32_bf16(af[fm], bfr[fn], acc[fm][fn], 0, 0, 0);
  }
#pragma unroll
  for (int fm = 0; fm < 4; ++fm){
#pragma unroll
    for (int r = 0; r < 4; ++r){
      size_t gro = (size_t)(m0 + wm + fm * 16 + quad * 4 + r) * DIM + n0 + wn + l16;
#pragma unroll
      for (int fn = 0; fn < 8; ++fn)
        H8[gro + fn * 16] = f2fp8(acc[fm][fn][r]);
    }
  }
}

// R16 split-DIM gather: TWO sequential passes, each touching a 256-col half
// of h8 (12.8MB footprint vs 25.6 -> closer to 32MB aggregate L2, less thrash;
// measured: full-pass FETCH 130MB = ~46% hit on the 230MB logical gather).
// Per pass: lane loads 4B (4 fp8 ch), 2 pk-FMAs/edge, softmax recomputed
// (cheap), half-width bconv/Wg/hconv8. Pass1 accumulates gate partial.
__global__ __launch_bounds__(256, 8) void k_edge(const int* __restrict__ cnt, const int2* __restrict__ cap,
                                              const float* __restrict__ a_d,
                                              const unsigned char* __restrict__ h8,
                                              const float* __restrict__ bconv,
                                              const float* __restrict__ Wg, const float* __restrict__ bg,
                                              unsigned char* __restrict__ hconv8, float* __restrict__ gate,
                                              int colofs, int pass){
  int wid = threadIdx.x >> 6, lane = threadIdx.x & 63;
  for (int i = blockIdx.x * 4 + wid; i < N_NODES; i += EDGE_BLOCKS * 4){
    int deg = cnt[i]; if (deg > CAPE) deg = CAPE;
    const int2* row = cap + (size_t)i * CAPE;
    float adi = a_d[i];
    f32x2 ac[2] = {};

    if (deg <= 64){
      int off_l = 0;
      float x0 = 0.f;
      if (lane < deg){
        int2 c = row[lane]; off_l = c.x;
        float e = __int_as_float(c.y) + adi; e = (e > 0.f) ? e : 0.2f * e;
        x0 = __expf(e);
      }
      float inv = 1.f / (wredSum(x0) + 1e-16f);
      float x0n = x0 * inv;
      int degc = (deg + 3) & ~3;                        // multiple of 4, >= 4

      auto FETCH = [&](int jj, unsigned& u, float& al){
        int off = __builtin_amdgcn_readlane(off_l, jj); // SGPR; pad lanes -> 0
        al = rlanef(x0n, jj);                           // SGPR; pad lanes -> 0
        u = *((const unsigned*)(h8 + off + colofs) + lane);  // 4B/lane
      };
      unsigned u0, u1, u2, u3;
      float f0, f1, f2, f3;
      FETCH(0, u0, f0); FETCH(1, u1, f1); FETCH(2, u2, f2); FETCH(3, u3, f3);
      for (int j = 0; j < degc; j += 4){
        consume4(ac, u0, f0); if (j + 4 < degc) FETCH(j + 4, u0, f0);
        consume4(ac, u1, f1); if (j + 5 < degc) FETCH(j + 5, u1, f1);
        consume4(ac, u2, f2); if (j + 6 < degc) FETCH(j + 6, u2, f2);
        consume4(ac, u3, f3); if (j + 7 < degc) FETCH(j + 7, u3, f3);
      }
    } else {
      // 64 < deg <= 128 (rare): two lane-batches, unpipelined consume
      int o0 = 0, o1 = 0;
      float x0 = 0.f, x1 = 0.f;
      {
        int2 c = row[lane]; o0 = c.x;                 // lane < 64 <= deg
        float e = __int_as_float(c.y) + adi; e = (e > 0.f) ? e : 0.2f * e;
        x0 = __expf(e);
      }
      if (64 + lane < deg){
        int2 c = row[64 + lane]; o1 = c.x;
        float e = __int_as_float(c.y) + adi; e = (e > 0.f) ? e : 0.2f * e;
        x1 = __expf(e);
      }
      float inv = 1.f / (wredSum(x0 + x1) + 1e-16f);
      float xn0 = x0 * inv, xn1 = x1 * inv;
      for (int j = 0; j < deg; ++j){
        int off  = __builtin_amdgcn_readlane((j < 64) ? o0 : o1, j & 63);
        float al = rlanef((j < 64) ? xn0 : xn1, j & 63);
        unsigned u = *((const unsigned*)(h8 + off + colofs) + lane);
        consume4(ac, u, al);
      }
    }

    float4 bc = ((const float4*)(bconv + colofs))[lane];
    ac[0][0] += bc.x; ac[0][1] += bc.y; ac[1][0] += bc.z; ac[1][1] += bc.w;
    unsigned w = pk4f8(ac[0][0], ac[0][1], ac[1][0], ac[1][1]);
    ((unsigned*)(hconv8 + (size_t)i * DIM + colofs))[lane] = w;
    float4 wg = ((const float4*)(Wg + colofs))[lane];
    float gp = ac[0][0]*wg.x + ac[0][1]*wg.y + ac[1][0]*wg.z + ac[1][1]*wg.w;
    gp = wredSum(gp);
    if (lane == 0){
      if (pass == 0) gate[i] = gp;
      else           gate[i] = gate[i] + gp + bg[0];
    }
  }
}

// per-graph sum of exp(gate), LDS-aggregated (~784 global atomics total)
__global__ void k_gsum(const float* __restrict__ gate, const int* __restrict__ batch, float* gsum){
  __shared__ float sm[GQ];
  int t = threadIdx.x, i = blockIdx.x * 512 + t;
  if (t < GQ) sm[t] = 0.f;
  __syncthreads();
  if (i < N_NODES) atomicAdd(&sm[batch[i]], __expf(gate[i]));
  __syncthreads();
  if (t < GQ && sm[t] != 0.f) atomicAdd(&gsum[t], sm[t]);
}

// fused: g = exp(gate)/gsum (written to out_g) + pp[g][c] = sum g_i*hconv[i][c]
__global__ __launch_bounds__(256) void k_pool(const unsigned char* __restrict__ hconv8,
                                              const int* __restrict__ batch,
                                              const float* __restrict__ gate,
                                              const float* __restrict__ gsum,
                                              float* __restrict__ out_g, float* pp){
  __shared__ float gv_s[128];
  __shared__ int b_s[128];
  int t = threadIdx.x;
  int base = blockIdx.x * 128;
  if (t < 128){
    int i = base + t;
    if (i < N_NODES){
      int b = batch[i];
      float gv = __expf(gate[i]) / (gsum[b] + 1e-16f);
      gv_s[t] = gv; b_s[t] = b;
      out_g[i] = gv;
    } else { gv_s[t] = 0.f; b_s[t] = -1; }
  }
  __syncthreads();
  int lim = N_NODES - base; if (lim > 128) lim = 128;
  float ax = 0.f, ay = 0.f;
  int cur = b_s[0];
#pragma unroll 4
  for (int r = 0; r < lim; ++r){
    int b = b_s[r];
    float gv = gv_s[r];
    if (b != cur){
      atomicAdd(&pp[cur * DIM + 2 * t], ax);
      atomicAdd(&pp[cur * DIM + 2 * t + 1], ay);
      ax = ay = 0.f; cur = b;
    }
    unsigned us = *(const unsigned short*)(hconv8 + (size_t)(base + r) * DIM + 2 * t);
    auto p = __builtin_amdgcn_cvt_pk_f32_fp8(us, false);
    ax += gv * p[0];
    ay += gv * p[1];
  }
  if (cur >= 0){
    atomicAdd(&pp[cur * DIM + 2 * t], ax);
    atomicAdd(&pp[cur * DIM + 2 * t + 1], ay);
  }
}

// dst[g][j] = (relu?)(src[g][:] . WT[j][:] + bias[j]) — 128 blocks, wave per column
template<bool RELU>
__global__ void k_headA(const float* __restrict__ src, const float* __restrict__ WT,
                        const float* __restrict__ bias, float* dst){
  __shared__ float sp[GQ * DIM];
  int t = threadIdx.x;
  for (int idx = t; idx < GQ * DIM; idx += 256) sp[idx] = src[idx];
  __syncthreads();
  int wid = t >> 6, lane = t & 63;
  int j = blockIdx.x * 4 + wid;
  const float4* wr = (const float4*)(WT + (size_t)j * DIM);
  float4 w0 = wr[lane * 2], w1 = wr[lane * 2 + 1];
  float bj = bias[j];
#pragma unroll
  for (int g = 0; g < GQ; ++g){
    const float* pg = sp + g * DIM + lane * 8;
    float s = w0.x*pg[0] + w0.y*pg[1] + w0.z*pg[2] + w0.w*pg[3]
            + w1.x*pg[4] + w1.y*pg[5] + w1.z*pg[6] + w1.w*pg[7];
    s = wredSum(s);
    if (lane == 0){
      s += bj;
      if (RELU) s = fmaxf(s, 0.f);
      dst[g * DIM + j] = s;
    }
  }
}

// out[g] = sigmoid(z1[g] . W2 + b2) — 1 block, 8 waves
__global__ void k_headC(const float* __restrict__ z1, const float* __restrict__ W2,
                        const float* __restrict__ b2, float* __restrict__ out){
  int wv = threadIdx.x >> 6, lane = threadIdx.x & 63;
  const float4* zr = (const float4*)(z1 + (size_t)wv * DIM);
  const float4* w4 = (const float4*)W2;
  float s = dot4(zr[lane * 2], w4[lane * 2]) + dot4(zr[lane * 2 + 1], w4[lane * 2 + 1]);
  s = wredSum(s);
  if (lane == 0) out[wv] = 1.f / (1.f + __expf(-(s + b2[0])));
}

// ---------------- launch ----------------
extern "C" void kernel_launch(void* const* d_in, const int* in_sizes, int n_in,
                              void* d_out, int out_size, void* d_ws, size_t ws_size,
                              hipStream_t stream){
  (void)in_sizes; (void)n_in; (void)out_size; (void)ws_size;
  const float* x   = (const float*)d_in[0];
  const int*   ei  = (const int*)d_in[1];
  const int*   bat = (const int*)d_in[2];
  const float* W   = (const float*)d_in[3];
  const float* atS = (const float*)d_in[4];
  const float* atD = (const float*)d_in[5];
  const float* bcv = (const float*)d_in[6];
  const float* Wg  = (const float*)d_in[7];
  const float* bg  = (const float*)d_in[8];
  const float* Wn  = (const float*)d_in[9];
  const float* bn  = (const float*)d_in[10];
  const float* W1  = (const float*)d_in[11];
  const float* b1  = (const float*)d_in[12];
  const float* W2  = (const float*)d_in[13];
  const float* b2  = (const float*)d_in[14];
  float* out = (float*)d_out;
  char* ws = (char*)d_ws;

  unsigned short* x_bf   = (unsigned short*)(ws + OFF_XBF);
  unsigned char*  h8     = (unsigned char*)(ws + OFF_HF8);
  unsigned char*  hconv8 = (unsigned char*)(ws + OFF_HCV8);
  int2*           cap    = (int2*)(ws + OFF_CAP);
  unsigned short* Wt_bf  = (unsigned short*)(ws + OFF_WTBF);
  float* WnT  = (float*)(ws + OFF_WNT);
  float* W1T  = (float*)(ws + OFF_W1T);
  float* ws_s = (float*)(ws + OFF_WSS);
  float* ws_d = (float*)(ws + OFF_WSD);
  float* a_s  = (float*)(ws + OFF_AS);
  float* a_d  = (float*)(ws + OFF_AD);
  float* gate = (float*)(ws + OFF_GATE);
  int* cnt  = (int*)(ws + OFF_CNT);
  float* gsum = (float*)(ws + OFF_GSUM);
  float* pp   = (float*)(ws + OFF_PP);
  float* pool = (float*)(ws + OFF_POOL);
  float* z1   = (float*)(ws + OFF_Z1);

  hipLaunchKernelGGL(k_setup, dim3(NBLK_SCAN + 192), dim3(256), 0, stream,
                     W, atS, atD, Wn, W1, ws_s, ws_d, Wt_bf, WnT, W1T, cnt, gsum, pp);
  hipLaunchKernelGGL(k_cast, dim3(N_PAD / 4), dim3(256), 0, stream,
                     x, ws_s, ws_d, x_bf, a_s, a_d, cap);
  hipLaunchKernelGGL(k_fill, dim3((EE + 255) / 256), dim3(256), 0, stream, ei, a_s, cnt, cap);
  hipLaunchKernelGGL(k_gemm, dim3(N_PAD / 128, 2), dim3(256), 0, stream, x_bf, Wt_bf, h8);
  hipLaunchKernelGGL(k_edge, dim3(EDGE_BLOCKS), dim3(256), 0, stream,
                     cnt, cap, a_d, h8, bcv, Wg, bg, hconv8, gate, 0, 0);
  hipLaunchKernelGGL(k_edge, dim3(EDGE_BLOCKS), dim3(256), 0, stream,
                     cnt, cap, a_d, h8, bcv, Wg, bg, hconv8, gate, 256, 1);
  hipLaunchKernelGGL(k_gsum, dim3(98), dim3(512), 0, stream, gate, bat, gsum);
  hipLaunchKernelGGL(k_pool, dim3((N_NODES + 127) / 128), dim3(256), 0, stream,
                     hconv8, bat, gate, gsum, out + GQ, pp);
  hipLaunchKernelGGL((k_headA<false>), dim3(128), dim3(256), 0, stream, pp, WnT, bn, pool);
  hipLaunchKernelGGL((k_headA<true>),  dim3(128), dim3(256), 0, stream, pool, W1T, b1, z1);
  hipLaunchKernelGGL(k_headC, dim3(1), dim3(512), 0, stream, z1, W2, b2, out);
}

// Round 23
// 366.925 us; speedup vs baseline: 1.0856x; 1.0856x over previous
//
#include <hip/hip_runtime.h>
#include <stdint.h>

#define N_NODES 50000
#define N_PAD   50048      // 391 * 128
#define GQ      8
#define EE      400000
#define DIM     512
#define CAPE    128        // per-node edge-slot capacity (Poisson(8)+1 max ~35)
#define NBLK_SCAN 196
#define EDGE_BLOCKS 1024   // measured curve minimum: 37% occ, 130MB fetch, 65.5us

typedef __attribute__((ext_vector_type(8))) __bf16 bf16x8;
typedef __attribute__((ext_vector_type(4))) float f32x4;
typedef __attribute__((ext_vector_type(2))) float f32x2;

// ---------------- helpers ----------------
__device__ __forceinline__ unsigned short f2bf(float f){
  unsigned u = __float_as_uint(f);
  return (unsigned short)((u + 0x7fffu + ((u >> 16) & 1u)) >> 16);
}
__device__ __forceinline__ unsigned pk2(float lo, float hi){
  return (unsigned)f2bf(lo) | ((unsigned)f2bf(hi) << 16);
}
__device__ __forceinline__ float dot4(float4 a, float4 b){ return a.x*b.x + a.y*b.y + a.z*b.z + a.w*b.w; }
__device__ __forceinline__ float wredSum(float v){
#pragma unroll
  for (int o = 32; o > 0; o >>= 1) v += __shfl_xor(v, o, 64);
  return v;
}
__device__ __forceinline__ float rlanef(float v, int l){
  return __int_as_float(__builtin_amdgcn_readlane(__float_as_int(v), l));
}
__device__ __forceinline__ void gload_lds16(const void* g, void* l){
  __builtin_amdgcn_global_load_lds((__attribute__((address_space(1))) void*)g,
                                   (__attribute__((address_space(3))) void*)l, 16, 0, 0);
}
// fp8 e4m3 HW codec (self-consistent encode+decode on gfx950)
__device__ __forceinline__ unsigned char f2fp8(float x){
  return (unsigned char)__builtin_amdgcn_cvt_pk_fp8_f32(x, x, 0, false);
}
__device__ __forceinline__ unsigned pk4f8(float a, float b, float c, float d){
  unsigned w = (unsigned)__builtin_amdgcn_cvt_pk_fp8_f32(a, b, 0, false);
  return (unsigned)__builtin_amdgcn_cvt_pk_fp8_f32(c, d, (int)w, true);
}
// ac = float2[4]; al is wave-uniform (SGPR) -> v_pk_fma_f32 with SGPR scalar
__device__ __forceinline__ void consumeF8(f32x2* ac, uint2 u, float al){
  f32x2 p0 = __builtin_amdgcn_cvt_pk_f32_fp8(u.x, false);
  f32x2 p1 = __builtin_amdgcn_cvt_pk_f32_fp8(u.x, true);
  f32x2 p2 = __builtin_amdgcn_cvt_pk_f32_fp8(u.y, false);
  f32x2 p3 = __builtin_amdgcn_cvt_pk_f32_fp8(u.y, true);
  ac[0] += al * p0;
  ac[1] += al * p1;
  ac[2] += al * p2;
  ac[3] += al * p3;
}

// ---------------- workspace layout ----------------
static constexpr size_t AL(size_t x){ return (x + 255) & ~(size_t)255; }
static constexpr size_t OFF_XBF   = 0;
static constexpr size_t OFF_HF8   = OFF_XBF   + AL((size_t)N_PAD * DIM * 2);
static constexpr size_t OFF_HCV8  = OFF_HF8   + AL((size_t)N_PAD * DIM);
static constexpr size_t OFF_CAP   = OFF_HCV8  + AL((size_t)N_NODES * DIM);
static constexpr size_t OFF_WTBF  = OFF_CAP   + AL((size_t)N_NODES * CAPE * 8);
static constexpr size_t OFF_WNT   = OFF_WTBF  + AL((size_t)DIM * DIM * 2);
static constexpr size_t OFF_W1T   = OFF_WNT   + AL((size_t)DIM * DIM * 4);
static constexpr size_t OFF_WSS   = OFF_W1T   + AL((size_t)DIM * DIM * 4);
static constexpr size_t OFF_WSD   = OFF_WSS   + AL((size_t)DIM * 4);
static constexpr size_t OFF_AS    = OFF_WSD   + AL((size_t)DIM * 4);
static constexpr size_t OFF_AD    = OFF_AS    + AL((size_t)N_NODES * 4);
static constexpr size_t OFF_GATE  = OFF_AD    + AL((size_t)N_NODES * 4);
static constexpr size_t OFF_CNT   = OFF_GATE  + AL((size_t)N_NODES * 4);
static constexpr size_t OFF_GSUM  = OFF_CNT   + AL((size_t)N_NODES * 4);
static constexpr size_t OFF_PP    = OFF_GSUM  + AL((size_t)GQ * 4);
static constexpr size_t OFF_POOL  = OFF_PP    + AL((size_t)GQ * DIM * 4);
static constexpr size_t OFF_Z1    = OFF_POOL  + AL((size_t)GQ * DIM * 4);

// ---------------- kernels ----------------

// fused: init (cnt/gsum/pp) + ws_s/ws_d = W@att_{src,dst} + 3x 512x512 transpose
__global__ void k_setup(const float* __restrict__ W, const float* __restrict__ atS,
                        const float* __restrict__ atD, const float* __restrict__ Wn,
                        const float* __restrict__ W1,
                        float* ws_s, float* ws_d,
                        unsigned short* __restrict__ WtBf, float* __restrict__ WnT,
                        float* __restrict__ W1T,
                        int* cnt, float* gsum, float* pp){
  __shared__ float tile[64][65];
  int bx = blockIdx.x;
  if (bx < NBLK_SCAN){
    int i = bx * 256 + threadIdx.x;
    if (i < N_NODES) cnt[i] = 1;                    // slot 0 = self-loop
    if (i < GQ) gsum[i] = 0.f;
    if (i < GQ * DIM) pp[i] = 0.f;
    if (bx < 128){
      int wid = threadIdx.x >> 6, lane = threadIdx.x & 63;
      int k = bx * 4 + wid;                         // 0..511
      const float4* row = (const float4*)(W + (size_t)k * DIM);
      float4 r0 = row[lane * 2], r1 = row[lane * 2 + 1];
      const float4* s4 = (const float4*)atS;
      const float4* d4 = (const float4*)atD;
      float vs = dot4(r0, s4[lane * 2]) + dot4(r1, s4[lane * 2 + 1]);
      float vd = dot4(r0, d4[lane * 2]) + dot4(r1, d4[lane * 2 + 1]);
      vs = wredSum(vs); vd = wredSum(vd);
      if (lane == 0){ ws_s[k] = vs; ws_d[k] = vd; }
    }
  } else {
    int tb = bx - NBLK_SCAN;
    int y = tb >> 6, bq = tb & 63;
    const float* src = (y == 0) ? W : (y == 1) ? Wn : W1;
    int bi = bq & 7, bj = bq >> 3;
    int r0 = bi * 64, c0 = bj * 64;
#pragma unroll
    for (int ii = 0; ii < 16; ++ii){
      int idx = ii * 256 + threadIdx.x;
      int r = idx >> 6, c = idx & 63;
      tile[r][c] = src[(size_t)(r0 + r) * DIM + c0 + c];
    }
    __syncthreads();
#pragma unroll
    for (int ii = 0; ii < 16; ++ii){
      int idx = ii * 256 + threadIdx.x;
      int cc = idx >> 6, rr = idx & 63;
      float v = tile[rr][cc];
      size_t o = (size_t)(c0 + cc) * DIM + r0 + rr;
      if (y == 0) WtBf[o] = f2bf(v);
      else if (y == 1) WnT[o] = v;
      else W1T[o] = v;
    }
  }
}

// cast x -> bf16 (zero pad rows), a_s/a_d per row, write self-loop cap slot 0
__global__ __launch_bounds__(256) void k_cast(const float* __restrict__ x,
                                              const float* __restrict__ ws_s,
                                              const float* __restrict__ ws_d,
                                              unsigned short* __restrict__ x_bf,
                                              float* __restrict__ a_s, float* __restrict__ a_d,
                                              int2* __restrict__ cap){
  int wid = threadIdx.x >> 6, lane = threadIdx.x & 63;
  size_t i = (size_t)blockIdx.x * 4 + wid;
  if (i >= N_PAD) return;
  unsigned short* orow = x_bf + i * DIM;
  if (i >= N_NODES){
    ((uint4*)orow)[lane] = make_uint4(0, 0, 0, 0);
    return;
  }
  const float4* xr = (const float4*)(x + i * DIM);
  float4 v0 = xr[lane * 2], v1 = xr[lane * 2 + 1];
  ((uint4*)orow)[lane] = make_uint4(pk2(v0.x, v0.y), pk2(v0.z, v0.w), pk2(v1.x, v1.y), pk2(v1.z, v1.w));
  const float4* s4 = (const float4*)ws_s;
  const float4* d4 = (const float4*)ws_d;
  float vs = dot4(v0, s4[lane * 2]) + dot4(v1, s4[lane * 2 + 1]);
  float vd = dot4(v0, d4[lane * 2]) + dot4(v1, d4[lane * 2 + 1]);
  vs = wredSum(vs); vd = wredSum(vd);
  if (lane == 0){
    a_s[i] = vs; a_d[i] = vd;
    cap[i * CAPE] = make_int2((int)(i << 9), __float_as_int(vs));   // self-loop: byte offset
  }
}

// append edges into fixed-capacity per-dst rows; store PRE-SHIFTED byte offset
__global__ void k_fill(const int* __restrict__ ei, const float* __restrict__ a_s,
                       int* cnt, int2* __restrict__ cap){
  int e = blockIdx.x * 256 + threadIdx.x;
  if (e < EE){
    int s = ei[e], d = ei[EE + e];
    int p = atomicAdd(&cnt[d], 1);
    if (p < CAPE) cap[(size_t)d * CAPE + p] = make_int2(s << 9, __float_as_int(a_s[s]));
  }
}

// h = x_bf @ W (Bt = W^T, bf16). 128x256 strip tile, 16x16x32 MFMA, XOR bank swizzle.
// Epilogue stores h as fp8 e4m3 (halves k_edge's gather bytes; error budget ok).
__global__ __launch_bounds__(256, 2) void k_gemm(const unsigned short* __restrict__ A,
                                                 const unsigned short* __restrict__ Bt,
                                                 unsigned char* __restrict__ H8){
  __shared__ unsigned short As[128 * 32];   // 8 KB
  __shared__ unsigned short Bs[256 * 32];   // 16 KB
  const int tid = threadIdx.x;
  const int wid = tid >> 6, lane = tid & 63, quad = lane >> 4, l16 = lane & 15;
  const int m0 = blockIdx.x * 128, n0 = blockIdx.y * 256;
  const int wm = (wid & 1) * 64, wn = (wid >> 1) * 128;
  const int qa = quad ^ ((l16 >> 1) & 3);           // swizzled chunk for reads
  f32x4 acc[4][8] = {};
  for (int kt = 0; kt < 16; ++kt){
    const int k0 = kt * 32;
    __syncthreads();
#pragma unroll
    for (int r = 0; r < 2; ++r){                    // A: 512 16B-chunks
      int p = r * 256 + tid;
      int mm = p >> 2;
      int qg = (p & 3) ^ ((mm >> 1) & 3);
      gload_lds16(A + (size_t)(m0 + mm) * DIM + k0 + qg * 8,
                  As + (size_t)(r * 256 + wid * 64) * 8);
    }
#pragma unroll
    for (int r = 0; r < 4; ++r){                    // B: 1024 16B-chunks
      int p = r * 256 + tid;
      int mm = p >> 2;
      int qg = (p & 3) ^ ((mm >> 1) & 3);
      gload_lds16(Bt + (size_t)(n0 + mm) * DIM + k0 + qg * 8,
                  Bs + (size_t)(r * 256 + wid * 64) * 8);
    }
    __syncthreads();
    bf16x8 af[4], bfr[8];
#pragma unroll
    for (int f = 0; f < 4; ++f)
      af[f]  = *(const bf16x8*)(As + (wm + f * 16 + l16) * 32 + qa * 8);
#pragma unroll
    for (int f = 0; f < 8; ++f)
      bfr[f] = *(const bf16x8*)(Bs + (wn + f * 16 + l16) * 32 + qa * 8);
#pragma unroll
    for (int fm = 0; fm < 4; ++fm)
#pragma unroll
      for (int fn = 0; fn < 8; ++fn)
        acc[fm][fn] = __builtin_amdgcn_mfma_f32_16x16x32_bf16(af[fm], bfr[fn], acc[fm][fn], 0, 0, 0);
  }
#pragma unroll
  for (int fm = 0; fm < 4; ++fm){
#pragma unroll
    for (int r = 0; r < 4; ++r){
      size_t gro = (size_t)(m0 + wm + fm * 16 + quad * 4 + r) * DIM + n0 + wn + l16;
#pragma unroll
      for (int fn = 0; fn < 8; ++fn)
        H8[gro + fn * 16] = f2fp8(acc[fm][fn][r]);
    }
  }
}

// one PERSISTENT wave per node stream (grid-stride over nodes).
// R14-measured best: padded depth-4 pipeline, EDGE_BLOCKS=1024 (curve min:
// 37% occ, 130MB fetch, 65.5us). R16 dbuf-gemm: neutral. R19 split-DIM:
// REGRESSED +28us (first-touch misses dominate, not capacity) -> reverted.
// k_edge floor: 190MB traffic at ~3 TB/s ~= 63us; we are at it.
__global__ __launch_bounds__(256, 8) void k_edge(const int* __restrict__ cnt, const int2* __restrict__ cap,
                                              const float* __restrict__ a_d,
                                              const unsigned char* __restrict__ h8,
                                              const float* __restrict__ bconv,
                                              const float* __restrict__ Wg, const float* __restrict__ bg,
                                              unsigned char* __restrict__ hconv8, float* __restrict__ gate){
  int wid = threadIdx.x >> 6, lane = threadIdx.x & 63;
  for (int i = blockIdx.x * 4 + wid; i < N_NODES; i += EDGE_BLOCKS * 4){
    int deg = cnt[i]; if (deg > CAPE) deg = CAPE;
    const int2* row = cap + (size_t)i * CAPE;
    float adi = a_d[i];
    f32x2 ac[4] = {};

    if (deg <= 64){
      int off_l = 0;
      float x0 = 0.f;
      if (lane < deg){
        int2 c = row[lane]; off_l = c.x;
        float e = __int_as_float(c.y) + adi; e = (e > 0.f) ? e : 0.2f * e;
        x0 = __expf(e);
      }
      float inv = 1.f / (wredSum(x0) + 1e-16f);
      float x0n = x0 * inv;
      int degc = (deg + 3) & ~3;                        // multiple of 4, >= 4

      auto FETCH = [&](int jj, uint2& u, float& al){
        int off = __builtin_amdgcn_readlane(off_l, jj); // SGPR; pad lanes -> 0
        al = rlanef(x0n, jj);                           // SGPR; pad lanes -> 0
        u = *((const uint2*)(h8 + off) + lane);         // saddr + lane*8
      };
      uint2 u0, u1, u2, u3;
      float f0, f1, f2, f3;
      FETCH(0, u0, f0); FETCH(1, u1, f1); FETCH(2, u2, f2); FETCH(3, u3, f3);
      for (int j = 0; j < degc; j += 4){
        consumeF8(ac, u0, f0); if (j + 4 < degc) FETCH(j + 4, u0, f0);
        consumeF8(ac, u1, f1); if (j + 5 < degc) FETCH(j + 5, u1, f1);
        consumeF8(ac, u2, f2); if (j + 6 < degc) FETCH(j + 6, u2, f2);
        consumeF8(ac, u3, f3); if (j + 7 < degc) FETCH(j + 7, u3, f3);
      }
    } else {
      // 64 < deg <= 128 (rare): two lane-batches, unpipelined consume
      int o0 = 0, o1 = 0;
      float x0 = 0.f, x1 = 0.f;
      {
        int2 c = row[lane]; o0 = c.x;                 // lane < 64 <= deg
        float e = __int_as_float(c.y) + adi; e = (e > 0.f) ? e : 0.2f * e;
        x0 = __expf(e);
      }
      if (64 + lane < deg){
        int2 c = row[64 + lane]; o1 = c.x;
        float e = __int_as_float(c.y) + adi; e = (e > 0.f) ? e : 0.2f * e;
        x1 = __expf(e);
      }
      float inv = 1.f / (wredSum(x0 + x1) + 1e-16f);
      float xn0 = x0 * inv, xn1 = x1 * inv;
      for (int j = 0; j < deg; ++j){
        int off  = __builtin_amdgcn_readlane((j < 64) ? o0 : o1, j & 63);
        float al = rlanef((j < 64) ? xn0 : xn1, j & 63);
        uint2 u = *((const uint2*)(h8 + off) + lane);
        consumeF8(ac, u, al);
      }
    }

    float4 bc0 = ((const float4*)bconv)[lane * 2];
    float4 bc1 = ((const float4*)bconv)[lane * 2 + 1];
    ac[0][0] += bc0.x; ac[0][1] += bc0.y; ac[1][0] += bc0.z; ac[1][1] += bc0.w;
    ac[2][0] += bc1.x; ac[2][1] += bc1.y; ac[3][0] += bc1.z; ac[3][1] += bc1.w;
    unsigned w0 = pk4f8(ac[0][0], ac[0][1], ac[1][0], ac[1][1]);
    unsigned w1 = pk4f8(ac[2][0], ac[2][1], ac[3][0], ac[3][1]);
    ((uint2*)(hconv8 + (size_t)i * DIM))[lane] = make_uint2(w0, w1);
    float4 wg0 = ((const float4*)Wg)[lane * 2];
    float4 wg1 = ((const float4*)Wg)[lane * 2 + 1];
    float gp = ac[0][0]*wg0.x + ac[0][1]*wg0.y + ac[1][0]*wg0.z + ac[1][1]*wg0.w
             + ac[2][0]*wg1.x + ac[2][1]*wg1.y + ac[3][0]*wg1.z + ac[3][1]*wg1.w;
    gp = wredSum(gp);
    if (lane == 0) gate[i] = gp + bg[0];
  }
}

// per-graph sum of exp(gate), LDS-aggregated (~784 global atomics total)
__global__ void k_gsum(const float* __restrict__ gate, const int* __restrict__ batch, float* gsum){
  __shared__ float sm[GQ];
  int t = threadIdx.x, i = blockIdx.x * 512 + t;
  if (t < GQ) sm[t] = 0.f;
  __syncthreads();
  if (i < N_NODES) atomicAdd(&sm[batch[i]], __expf(gate[i]));
  __syncthreads();
  if (t < GQ && sm[t] != 0.f) atomicAdd(&gsum[t], sm[t]);
}

// fused: g = exp(gate)/gsum (written to out_g) + pp[g][c] = sum g_i*hconv[i][c]
__global__ __launch_bounds__(256) void k_pool(const unsigned char* __restrict__ hconv8,
                                              const int* __restrict__ batch,
                                              const float* __restrict__ gate,
                                              const float* __restrict__ gsum,
                                              float* __restrict__ out_g, float* pp){
  __shared__ float gv_s[128];
  __shared__ int b_s[128];
  int t = threadIdx.x;
  int base = blockIdx.x * 128;
  if (t < 128){
    int i = base + t;
    if (i < N_NODES){
      int b = batch[i];
      float gv = __expf(gate[i]) / (gsum[b] + 1e-16f);
      gv_s[t] = gv; b_s[t] = b;
      out_g[i] = gv;
    } else { gv_s[t] = 0.f; b_s[t] = -1; }
  }
  __syncthreads();
  int lim = N_NODES - base; if (lim > 128) lim = 128;
  float ax = 0.f, ay = 0.f;
  int cur = b_s[0];
#pragma unroll 4
  for (int r = 0; r < lim; ++r){
    int b = b_s[r];
    float gv = gv_s[r];
    if (b != cur){
      atomicAdd(&pp[cur * DIM + 2 * t], ax);
      atomicAdd(&pp[cur * DIM + 2 * t + 1], ay);
      ax = ay = 0.f; cur = b;
    }
    unsigned us = *(const unsigned short*)(hconv8 + (size_t)(base + r) * DIM + 2 * t);
    auto p = __builtin_amdgcn_cvt_pk_f32_fp8(us, false);
    ax += gv * p[0];
    ay += gv * p[1];
  }
  if (cur >= 0){
    atomicAdd(&pp[cur * DIM + 2 * t], ax);
    atomicAdd(&pp[cur * DIM + 2 * t + 1], ay);
  }
}

// dst[g][j] = (relu?)(src[g][:] . WT[j][:] + bias[j]) — 128 blocks, wave per column
template<bool RELU>
__global__ void k_headA(const float* __restrict__ src, const float* __restrict__ WT,
                        const float* __restrict__ bias, float* dst){
  __shared__ float sp[GQ * DIM];
  int t = threadIdx.x;
  for (int idx = t; idx < GQ * DIM; idx += 256) sp[idx] = src[idx];
  __syncthreads();
  int wid = t >> 6, lane = t & 63;
  int j = blockIdx.x * 4 + wid;
  const float4* wr = (const float4*)(WT + (size_t)j * DIM);
  float4 w0 = wr[lane * 2], w1 = wr[lane * 2 + 1];
  float bj = bias[j];
#pragma unroll
  for (int g = 0; g < GQ; ++g){
    const float* pg = sp + g * DIM + lane * 8;
    float s = w0.x*pg[0] + w0.y*pg[1] + w0.z*pg[2] + w0.w*pg[3]
            + w1.x*pg[4] + w1.y*pg[5] + w1.z*pg[6] + w1.w*pg[7];
    s = wredSum(s);
    if (lane == 0){
      s += bj;
      if (RELU) s = fmaxf(s, 0.f);
      dst[g * DIM + j] = s;
    }
  }
}

// out[g] = sigmoid(z1[g] . W2 + b2) — 1 block, 8 waves
__global__ void k_headC(const float* __restrict__ z1, const float* __restrict__ W2,
                        const float* __restrict__ b2, float* __restrict__ out){
  int wv = threadIdx.x >> 6, lane = threadIdx.x & 63;
  const float4* zr = (const float4*)(z1 + (size_t)wv * DIM);
  const float4* w4 = (const float4*)W2;
  float s = dot4(zr[lane * 2], w4[lane * 2]) + dot4(zr[lane * 2 + 1], w4[lane * 2 + 1]);
  s = wredSum(s);
  if (lane == 0) out[wv] = 1.f / (1.f + __expf(-(s + b2[0])));
}

// ---------------- launch ----------------
extern "C" void kernel_launch(void* const* d_in, const int* in_sizes, int n_in,
                              void* d_out, int out_size, void* d_ws, size_t ws_size,
                              hipStream_t stream){
  (void)in_sizes; (void)n_in; (void)out_size; (void)ws_size;
  const float* x   = (const float*)d_in[0];
  const int*   ei  = (const int*)d_in[1];
  const int*   bat = (const int*)d_in[2];
  const float* W   = (const float*)d_in[3];
  const float* atS = (const float*)d_in[4];
  const float* atD = (const float*)d_in[5];
  const float* bcv = (const float*)d_in[6];
  const float* Wg  = (const float*)d_in[7];
  const float* bg  = (const float*)d_in[8];
  const float* Wn  = (const float*)d_in[9];
  const float* bn  = (const float*)d_in[10];
  const float* W1  = (const float*)d_in[11];
  const float* b1  = (const float*)d_in[12];
  const float* W2  = (const float*)d_in[13];
  const float* b2  = (const float*)d_in[14];
  float* out = (float*)d_out;
  char* ws = (char*)d_ws;

  unsigned short* x_bf   = (unsigned short*)(ws + OFF_XBF);
  unsigned char*  h8     = (unsigned char*)(ws + OFF_HF8);
  unsigned char*  hconv8 = (unsigned char*)(ws + OFF_HCV8);
  int2*           cap    = (int2*)(ws + OFF_CAP);
  unsigned short* Wt_bf  = (unsigned short*)(ws + OFF_WTBF);
  float* WnT  = (float*)(ws + OFF_WNT);
  float* W1T  = (float*)(ws + OFF_W1T);
  float* ws_s = (float*)(ws + OFF_WSS);
  float* ws_d = (float*)(ws + OFF_WSD);
  float* a_s  = (float*)(ws + OFF_AS);
  float* a_d  = (float*)(ws + OFF_AD);
  float* gate = (float*)(ws + OFF_GATE);
  int* cnt  = (int*)(ws + OFF_CNT);
  float* gsum = (float*)(ws + OFF_GSUM);
  float* pp   = (float*)(ws + OFF_PP);
  float* pool = (float*)(ws + OFF_POOL);
  float* z1   = (float*)(ws + OFF_Z1);

  hipLaunchKernelGGL(k_setup, dim3(NBLK_SCAN + 192), dim3(256), 0, stream,
                     W, atS, atD, Wn, W1, ws_s, ws_d, Wt_bf, WnT, W1T, cnt, gsum, pp);
  hipLaunchKernelGGL(k_cast, dim3(N_PAD / 4), dim3(256), 0, stream,
                     x, ws_s, ws_d, x_bf, a_s, a_d, cap);
  hipLaunchKernelGGL(k_fill, dim3((EE + 255) / 256), dim3(256), 0, stream, ei, a_s, cnt, cap);
  hipLaunchKernelGGL(k_gemm, dim3(N_PAD / 128, 2), dim3(256), 0, stream, x_bf, Wt_bf, h8);
  hipLaunchKernelGGL(k_edge, dim3(EDGE_BLOCKS), dim3(256), 0, stream,
                     cnt, cap, a_d, h8, bcv, Wg, bg, hconv8, gate);
  hipLaunchKernelGGL(k_gsum, dim3(98), dim3(512), 0, stream, gate, bat, gsum);
  hipLaunchKernelGGL(k_pool, dim3((N_NODES + 127) / 128), dim3(256), 0, stream,
                     hconv8, bat, gate, gsum, out + GQ, pp);
  hipLaunchKernelGGL((k_headA<false>), dim3(128), dim3(256), 0, stream, pp, WnT, bn, pool);
  hipLaunchKernelGGL((k_headA<true>),  dim3(128), dim3(256), 0, stream, pool, W1T, b1, z1);
  hipLaunchKernelGGL(k_headC, dim3(1), dim3(512), 0, stream, z1, W2, b2, out);
}